// Round 6
// baseline (478.485 us; speedup 1.0000x reference)
//
#include <hip/hip_runtime.h>
#include <stdint.h>

#define VV 128000
#define HN 4096
#define CAP 4096           // slow-kernel internal fast-path cap (r5)
#define CAPR 8192          // pipeline candidate cap per row
#define CHUNK_F4 4000      // 16000 elements per chunk, 8 chunks per row

typedef unsigned long long ull;

__device__ __forceinline__ uint32_t rotl32(uint32_t x, int r){ return (x << r) | (x >> (32 - r)); }

// Bit-exact replica of jax.random.exponential(key(42), (256,128000), f32) at flat
// index f, under jax_threefry_partitionable=True (bits = out0 ^ out1).
__device__ __forceinline__ float exp_noise(uint32_t f){
  const uint32_t ks0 = 0u, ks1 = 42u, ks2 = 0x1BD11BDAu ^ 0u ^ 42u;
  uint32_t x0 = 0u + ks0;
  uint32_t x1 = f + ks1;
#define R1(r) { x0 += x1; x1 = rotl32(x1, r); x1 ^= x0; }
  R1(13) R1(15) R1(26) R1(6)   x0 += ks1; x1 += ks2 + 1u;
  R1(17) R1(29) R1(16) R1(24)  x0 += ks2; x1 += ks0 + 2u;
  R1(13) R1(15) R1(26) R1(6)   x0 += ks0; x1 += ks1 + 3u;
  R1(17) R1(29) R1(16) R1(24)  x0 += ks1; x1 += ks2 + 4u;
  R1(13) R1(15) R1(26) R1(6)   x0 += ks2; x1 += ks0 + 5u;
#undef R1
  uint32_t bits = x0 ^ x1;
  float u = __uint_as_float((bits >> 9) | 0x3F800000u) - 1.0f;
  float e = -log1pf(-u);
  return fmaxf(e, 1e-10f);
}

__device__ __forceinline__ uint32_t fkey(float x){
  uint32_t u = __float_as_uint(x);
  return u ^ ((u & 0x80000000u) ? 0xFFFFFFFFu : 0x80000000u);
}
__device__ __forceinline__ float keyval(uint32_t k){
  uint32_t bits = (k & 0x80000000u) ? (k ^ 0x80000000u) : ~k;
  return __uint_as_float(bits);
}

// tid0-serial: move the t smallest of a[0..n) to front, return t-th smallest.
__device__ uint32_t select_tth_smallest(uint32_t* a, int n, int t){
  for (int i=0;i<t;i++){
    int mi=i; uint32_t mv=a[i];
    for (int j=i+1;j<n;j++) if (a[j]<mv){ mv=a[j]; mi=j; }
    a[mi]=a[i]; a[i]=mv;
  }
  return a[t-1];
}

// In-place inclusive SUFFIX sum over 4096 entries, shfl-based (2 barriers).
// NT threads, each owns 4096/NT contiguous entries. parts has NT/64 slots.
template<typename Tv, int NT>
__device__ __forceinline__ void suffix4096(Tv* h, Tv* parts, int tid){
  constexpr int E = HN/NT;
  const int base = tid*E;
  Tv loc[E]; Tv s = (Tv)0;
  #pragma unroll
  for (int i=E-1;i>=0;--i){ s += h[base+i]; loc[i]=s; }
  const int lane = tid & 63, w = tid >> 6;
  Tv v = s;
  #pragma unroll
  for (int d=1; d<64; d<<=1){
    Tv o = __shfl_down(v, (unsigned)d, 64);
    if (lane + d < 64) v += o;
  }
  if (lane == 0) parts[w] = v;
  __syncthreads();
  Tv woff = (Tv)0;
  for (int i=w+1;i<NT/64;i++) woff += parts[i];
  Tv lex = __shfl_down(v, 1u, 64);
  if (lane == 63) lex = (Tv)0;
  const Tv off = woff + lex;
  #pragma unroll
  for (int i=0;i<E;i++) h[base+i] = loc[i] + off;
  __syncthreads();
}

// ============================ K1: per-chunk histogram ============================
__global__ __launch_bounds__(256) void hist_kernel(const float* __restrict__ logits,
                                                   uint32_t* __restrict__ hists){
  __shared__ uint32_t h[HN];
  const int g = blockIdx.x, r = g >> 3, c = g & 7, tid = threadIdx.x;
  for (int i=tid;i<HN;i+=256) h[i]=0u;
  __syncthreads();
  const float4* rp = reinterpret_cast<const float4*>(logits + (size_t)r*VV) + (size_t)c*CHUNK_F4;
  for (int c0=tid;c0<CHUNK_F4;c0+=1024){
    float4 q[4]; bool g4[4];
    #pragma unroll
    for (int t=0;t<4;t++){ int cc=c0+t*256; g4[t]=(cc<CHUNK_F4); if(g4[t]) q[t]=rp[cc]; }
    #pragma unroll
    for (int t=0;t<4;t++) if(g4[t]){
      atomicAdd(&h[fkey(q[t].x)>>20],1u);
      atomicAdd(&h[fkey(q[t].y)>>20],1u);
      atomicAdd(&h[fkey(q[t].z)>>20],1u);
      atomicAdd(&h[fkey(q[t].w)>>20],1u);
    }
  }
  __syncthreads();
  uint32_t* gh = hists + (size_t)r*HN;
  for (int i=tid;i<HN;i+=256){ uint32_t v=h[i]; if (v) atomicAdd(&gh[i], v); }
}

// ============================ K2: candidate gather ============================
__global__ __launch_bounds__(256) void gather_kernel(const float* __restrict__ logits,
    const int* __restrict__ topks, const uint32_t* __restrict__ hists,
    uint32_t* __restrict__ ctrs, ull* __restrict__ cands){
  __shared__ uint32_t h[HN];
  __shared__ uint32_t parts[4];
  __shared__ int s_beta;
  const int g = blockIdx.x, r = g >> 3, c = g & 7, tid = threadIdx.x;
  const int k = topks[r];
  if (k < 1 || k >= VV) return;          // k==0 rows: slow kernel handles
  const uint32_t* gh = hists + (size_t)r*HN;
  for (int i=tid;i<HN;i+=256) h[i] = gh[i];
  __syncthreads();
  suffix4096<uint32_t,256>(h, parts, tid);
  if (tid==0) s_beta = 0;
  __syncthreads();
  for (int i=tid;i<HN;i+=256){
    uint32_t a=h[i], nn=(i+1<HN)?h[i+1]:0u;
    if (a >= (uint32_t)k && nn < (uint32_t)k) s_beta=i;
  }
  __syncthreads();
  const uint32_t beta=(uint32_t)s_beta;
  const uint32_t n = h[beta];            // exact candidate count, >= k
  if (n > CAPR){ if (c==0 && tid==0) ctrs[r] = n; return; }   // overflow marker
  ull* cr = cands + (size_t)r*CAPR;
  const float4* rp = reinterpret_cast<const float4*>(logits + (size_t)r*VV) + (size_t)c*CHUNK_F4;
  const uint32_t idx0 = (uint32_t)(c*CHUNK_F4*4);
  for (int c0=tid;c0<CHUNK_F4;c0+=1024){
    float4 q[4]; bool g4[4];
    #pragma unroll
    for (int t=0;t<4;t++){ int cc=c0+t*256; g4[t]=(cc<CHUNK_F4); if(g4[t]) q[t]=rp[cc]; }
    #pragma unroll
    for (int t=0;t<4;t++) if(g4[t]){
      float vs[4]={q[t].x,q[t].y,q[t].z,q[t].w};
      #pragma unroll
      for (int j=0;j<4;j++){
        uint32_t u=fkey(vs[j]);
        if ((u>>20) >= beta){
          uint32_t pos = atomicAdd(&ctrs[r], 1u);   // pos < n <= CAPR guaranteed
          cr[pos] = (((ull)u)<<32) | (idx0 + (uint32_t)(c0+t*256)*4u + (uint32_t)j);
        }
      }
    }
  }
}

// ============================ K3: in-LDS selection (no sort) ============================
__global__ __launch_bounds__(1024) void select_kernel(
    const float* __restrict__ temps, const int* __restrict__ topks, const float* __restrict__ topps,
    const uint32_t* __restrict__ ctrs, const ull* __restrict__ cands, int* __restrict__ outp){
  __shared__ ull ce[CAPR];             // 64 KB
  __shared__ uint32_t hbu[HN];         // 16 KB (u32 or float via alias)
  __shared__ uint32_t c3[256];
  __shared__ float    f3[256];
  __shared__ uint32_t tie[2048];       // 8 KB
  __shared__ uint32_t parts_u[16];
  __shared__ float    parts_f[16];
  __shared__ ull      parts_m[16];
  __shared__ int s_i1, s_i2, s_nt, s_tp, s_ntp, s_cnt;
  __shared__ uint32_t s_um, s_uk, s_idxk, s_up, s_idxp, s_cgt;
  __shared__ float s_Zk;

  const int r = blockIdx.x, tid = threadIdx.x;
  const int k = topks[r];
  if (k < 1 || k >= VV) return;
  const uint32_t ntot = ctrs[r];
  if (ntot > CAPR) return;             // overflow: slow kernel handles
  const int n = (int)ntot;
  const float T = temps[r];
  const float p = topps[r];
  const bool topp_act = (p > 0.f) && (p < 1.f);
  const ull* cr = cands + (size_t)r*CAPR;
  for (int i=tid;i<n;i+=1024) ce[i] = cr[i];
  __syncthreads();

  // row max key
  uint32_t um = 0u;
  for (int i=tid;i<n;i+=1024){ uint32_t u=(uint32_t)(ce[i]>>32); um = um>u?um:u; }
  {
    const int lane=tid&63, w=tid>>6; uint32_t v=um;
    #pragma unroll
    for (int d=32;d>0;d>>=1){ uint32_t o=__shfl_down(v,(unsigned)d,64); if(lane+d<64 && o>v) v=o; }
    if (lane==0) parts_u[w]=v;
    __syncthreads();
    if (tid==0){ uint32_t m2=0; for(int i=0;i<16;i++) if(parts_u[i]>m2) m2=parts_u[i]; s_um=m2; }
    __syncthreads();
    um = s_um;
  }
  const float xm = keyval(um)/T;

  // ---- top-k L1 (bits 31:20) ----
  for (int i=tid;i<HN;i+=1024) hbu[i]=0u;
  __syncthreads();
  for (int i=tid;i<n;i+=1024){ uint32_t u=(uint32_t)(ce[i]>>32); atomicAdd(&hbu[u>>20],1u); }
  __syncthreads();
  suffix4096<uint32_t,1024>(hbu, parts_u, tid);
  if (tid==0) s_i1=0;
  __syncthreads();
  for (int i=tid;i<HN;i+=1024){
    uint32_t a=hbu[i], nn=(i+1<HN)?hbu[i+1]:0u;
    if (a>=(uint32_t)k && nn<(uint32_t)k) s_i1=i;
  }
  __syncthreads();
  const int b1=s_i1;
  const uint32_t cA=(b1+1<HN)?hbu[b1+1]:0u;
  __syncthreads();
  // ---- top-k L2 (bits 19:8) ----
  for (int i=tid;i<HN;i+=1024) hbu[i]=0u;
  __syncthreads();
  for (int i=tid;i<n;i+=1024){ uint32_t u=(uint32_t)(ce[i]>>32); if ((int)(u>>20)==b1) atomicAdd(&hbu[(u>>8)&0xFFFu],1u); }
  __syncthreads();
  suffix4096<uint32_t,1024>(hbu, parts_u, tid);
  if (tid==0) s_i2=0;
  __syncthreads();
  for (int i=tid;i<HN;i+=1024){
    uint32_t a=cA+hbu[i], nn=cA+((i+1<HN)?hbu[i+1]:0u);
    if (a>=(uint32_t)k && nn<(uint32_t)k) s_i2=i;
  }
  __syncthreads();
  const int b2=s_i2;
  const uint32_t cB=cA+((b2+1<HN)?hbu[b2+1]:0u);
  // ---- top-k L3 (bits 7:0) ----
  if (tid<256) c3[tid]=0u;
  __syncthreads();
  const uint32_t t24=((uint32_t)b1<<12)|(uint32_t)b2;
  for (int i=tid;i<n;i+=1024){ uint32_t u=(uint32_t)(ce[i]>>32); if ((u>>8)==t24) atomicAdd(&c3[u&0xFFu],1u); }
  __syncthreads();
  if (tid==0){
    uint32_t rr=0; int b3=0;
    for (int i=255;i>=0;--i){ if (cB+rr+c3[i] >= (uint32_t)k){ b3=i; break; } rr+=c3[i]; }
    s_uk=(t24<<8)|(uint32_t)b3;
    s_cgt=cB+rr;
    s_nt=(int)c3[b3];
    s_cnt=0;
  }
  __syncthreads();
  const uint32_t uk=s_uk;
  const int tk=k-(int)s_cgt, nt=s_nt;
  uint32_t idxk=0xFFFFFFFFu;
  if (tk<nt){
    for (int i=tid;i<n;i+=1024){
      ull e=ce[i]; uint32_t u=(uint32_t)(e>>32);
      if (u==uk){ int pos=atomicAdd(&s_cnt,1); if (pos<2048) tie[pos]=(uint32_t)e; }
    }
    __syncthreads();
    if (tid==0){
      int m2=min(s_cnt,2048); int t=min(tk,m2);
      s_idxk=select_tth_smallest(tie,m2,t);
    }
    __syncthreads();
    idxk=s_idxk;
  }
  // ---- Zk over exact top-k set ----
  float zpart=0.f;
  for (int i=tid;i<n;i+=1024){
    ull e=ce[i]; uint32_t u=(uint32_t)(e>>32); uint32_t idx=(uint32_t)e;
    if ((u>uk)||(u==uk&&idx<=idxk)) zpart += expf(keyval(u)/T - xm);
  }
  {
    const int lane=tid&63,w=tid>>6; float v=zpart;
    #pragma unroll
    for (int d=32;d>0;d>>=1){ float o=__shfl_down(v,(unsigned)d,64); if(lane+d<64) v+=o; }
    if (lane==0) parts_f[w]=v;
    __syncthreads();
    if (tid==0){ float z=0.f; for(int i=0;i<16;i++) z+=parts_f[i]; s_Zk=z; }
    __syncthreads();
  }
  const float Zk=s_Zk;

  // ---- top-p (mass radix over kept-by-k candidates) ----
  uint32_t up=0u, idxp=0xFFFFFFFFu;
  const float tgt=p*Zk;
  const bool pall=(!topp_act)||(tgt>=Zk);
  if (!pall){
    float* hbf=(float*)hbu;
    for (int i=tid;i<HN;i+=1024) hbf[i]=0.f;
    __syncthreads();
    for (int i=tid;i<n;i+=1024){
      ull e=ce[i]; uint32_t u=(uint32_t)(e>>32); uint32_t idx=(uint32_t)e;
      if ((u>uk)||(u==uk&&idx<=idxk)) atomicAdd(&hbf[u>>20], expf(keyval(u)/T-xm));
    }
    __syncthreads();
    suffix4096<float,1024>(hbf, parts_f, tid);
    if (tid==0) s_i1=-1;
    __syncthreads();
    for (int i=tid;i<HN;i+=1024){
      float a=hbf[i], nn=(i+1<HN)?hbf[i+1]:0.f;
      if (a>tgt && nn<=tgt) s_i1=i;
    }
    __syncthreads();
    int bp1=s_i1;
    if (bp1<0){                     // defensive fp-wobble fallback
      if (tid==0) s_i1=HN;
      __syncthreads();
      for (int i=tid;i<HN;i+=1024){
        float a=hbf[i], nn=(i+1<HN)?hbf[i+1]:0.f;
        if (a>nn) atomicMin(&s_i1,i);
      }
      __syncthreads();
      bp1=(s_i1<HN)?s_i1:0;
    }
    const float Mab=(bp1+1<HN)?hbf[bp1+1]:0.f;
    __syncthreads();
    // L2
    for (int i=tid;i<HN;i+=1024) hbf[i]=0.f;
    __syncthreads();
    for (int i=tid;i<n;i+=1024){
      ull e=ce[i]; uint32_t u=(uint32_t)(e>>32); uint32_t idx=(uint32_t)e;
      if ((int)(u>>20)==bp1 && ((u>uk)||(u==uk&&idx<=idxk)))
        atomicAdd(&hbf[(u>>8)&0xFFFu], expf(keyval(u)/T-xm));
    }
    __syncthreads();
    suffix4096<float,1024>(hbf, parts_f, tid);
    if (tid==0) s_i2=-1;
    __syncthreads();
    for (int i=tid;i<HN;i+=1024){
      float a=Mab+hbf[i], nn=Mab+((i+1<HN)?hbf[i+1]:0.f);
      if (a>tgt && nn<=tgt) s_i2=i;
    }
    __syncthreads();
    int bp2=s_i2;
    if (bp2<0){
      if (tid==0) s_i2=HN;
      __syncthreads();
      for (int i=tid;i<HN;i+=1024){
        float a=hbf[i], nn=(i+1<HN)?hbf[i+1]:0.f;
        if (a>nn) atomicMin(&s_i2,i);
      }
      __syncthreads();
      bp2=(s_i2<HN)?s_i2:0;
    }
    const float Mab2=Mab+((bp2+1<HN)?hbf[bp2+1]:0.f);
    __syncthreads();
    // L3
    if (tid<256){ f3[tid]=0.f; c3[tid]=0u; }
    __syncthreads();
    const uint32_t p24=((uint32_t)bp1<<12)|(uint32_t)bp2;
    for (int i=tid;i<n;i+=1024){
      ull e=ce[i]; uint32_t u=(uint32_t)(e>>32); uint32_t idx=(uint32_t)e;
      if ((u>>8)==p24 && ((u>uk)||(u==uk&&idx<=idxk))){
        atomicAdd(&f3[u&0xFFu], expf(keyval(u)/T-xm));
        atomicAdd(&c3[u&0xFFu],1u);
      }
    }
    __syncthreads();
    if (tid==0){
      float run=0.f; int b3=-1; float mgt=0.f;
      for (int i=255;i>=0;--i){
        float sufn=run; run+=f3[i];
        if (Mab2+run>tgt && Mab2+sufn<=tgt){ b3=i; mgt=Mab2+sufn; break; }
      }
      if (b3<0){
        float run2=0.f;
        for (int i=255;i>=0;--i){ if (c3[i]>0u){ b3=i; mgt=Mab2+run2; } run2+=f3[i]; }
        if (b3<0){ b3=0; mgt=Mab2; }
      }
      const uint32_t upv=(p24<<8)|(uint32_t)b3;
      const int ntp=(int)c3[b3];
      const float ev=expf(keyval(upv)/T - xm);
      int t=0;
      for (int j=1;j<=ntp;j++){ float before=mgt+(float)(j-1)*ev; if (before<=tgt) t++; else break; }
      if (t<1) t=1;
      s_up=upv; s_tp=t; s_ntp=ntp; s_cnt=0;
    }
    __syncthreads();
    up=s_up;
    if (s_tp<s_ntp){
      for (int i=tid;i<n;i+=1024){
        ull e=ce[i]; uint32_t u=(uint32_t)(e>>32); uint32_t idx=(uint32_t)e;
        if (u==up && ((u>uk)||(u==uk&&idx<=idxk))){
          int pos=atomicAdd(&s_cnt,1); if (pos<2048) tie[pos]=idx;
        }
      }
      __syncthreads();
      if (tid==0){
        int m2=min(s_cnt,2048); int t=min(s_tp,m2);
        s_idxp=select_tth_smallest(tie,m2,t);
      }
      __syncthreads();
      idxp=s_idxp;
    }
  }

  // ---- final Gumbel-race argmax ----
  ull best=0ull;
  for (int i=tid;i<n;i+=1024){
    ull e=ce[i]; uint32_t u=(uint32_t)(e>>32); uint32_t idx=(uint32_t)e;
    bool kk=(u>uk)||(u==uk&&idx<=idxk);
    bool kp=pall||(u>up)||(u==up&&idx<=idxp);
    if (kk&&kp){
      float w=expf(keyval(u)/T-xm);
      float q=w/exp_noise((uint32_t)r*(uint32_t)VV+idx);
      ull pk=(((ull)__float_as_uint(q))<<32)|(uint32_t)(~idx);
      best=(pk>best)?pk:best;
    }
  }
  {
    const int lane=tid&63,w=tid>>6; ull v=best;
    #pragma unroll
    for (int d=32;d>0;d>>=1){ ull o=__shfl_down(v,(unsigned)d,64); if(lane+d<64 && o>v) v=o; }
    if (lane==0) parts_m[w]=v;
    __syncthreads();
    if (tid==0){
      ull m2=0ull; for(int i=0;i<16;i++) if (parts_m[i]>m2) m2=parts_m[i];
      outp[r]=(int)(~(uint32_t)(m2 & 0xFFFFFFFFull));
    }
  }
}

// ============================ K_slow: r5 kernel (mode 0 = standalone, mode 1 = k==0/overflow only)
__device__ void suffix_scan_u(uint32_t* h, uint32_t* tmp, int tid){
  const int base = tid * 4;
  uint32_t l0=h[base], l1=h[base+1], l2=h[base+2], l3=h[base+3];
  uint32_t s3=l3, s2=l2+s3, s1=l1+s2, s0=l0+s1;
  tmp[tid] = s0; __syncthreads();
  for (int d=1; d<1024; d<<=1){
    uint32_t add = (tid+d<1024) ? tmp[tid+d] : 0u;
    __syncthreads();
    tmp[tid] += add;
    __syncthreads();
  }
  uint32_t E = (tid+1<1024) ? tmp[tid+1] : 0u;
  h[base]=s0+E; h[base+1]=s1+E; h[base+2]=s2+E; h[base+3]=s3+E;
  __syncthreads();
}
__device__ void suffix_scan_f(float* h, float* tmp, int tid){
  const int base = tid * 4;
  float l0=h[base], l1=h[base+1], l2=h[base+2], l3=h[base+3];
  float s3=l3, s2=l2+s3, s1=l1+s2, s0=l0+s1;
  tmp[tid] = s0; __syncthreads();
  for (int d=1; d<1024; d<<=1){
    float add = (tid+d<1024) ? tmp[tid+d] : 0.f;
    __syncthreads();
    tmp[tid] += add;
    __syncthreads();
  }
  float E = (tid+1<1024) ? tmp[tid+1] : 0.f;
  h[base]=s0+E; h[base+1]=s1+E; h[base+2]=s2+E; h[base+3]=s3+E;
  __syncthreads();
}

__device__ void bitonic_sort(ull* a, int N, int tid){
  for (int len=2; len<=N; len<<=1){
    for (int j=len>>1; j>0; j>>=1){
      for (int i=tid; i<N; i+=1024){
        int l = i ^ j;
        if (l > i){
          ull x = a[i], y = a[l];
          bool asc = ((i & len) == 0);
          if (asc ? (x > y) : (x < y)){ a[i]=y; a[l]=x; }
        }
      }
      __syncthreads();
    }
  }
}

#define ROW4R_BEGIN \
    for (int c0 = tid; c0 < VV/4; c0 += 1024*4){ \
      float4 qv[4]; int cb[4]; bool gv[4]; \
      _Pragma("unroll") \
      for (int t=0;t<4;t++){ int cc = c0 + t*1024; gv[t] = (cc < VV/4); cb[t] = cc*4; if (gv[t]) qv[t] = rp[cc]; } \
      _Pragma("unroll") \
      for (int t=0;t<4;t++) if (gv[t]){ \
        float vs[4] = {qv[t].x, qv[t].y, qv[t].z, qv[t].w}; \
        _Pragma("unroll") \
        for (int j=0;j<4;j++){ \
          uint32_t u = fkey(vs[j]); \
          uint32_t idx = (uint32_t)(cb[t]+j); \
          (void)idx;
#define ROW4R_END } } }

#define ROW4_BEGIN \
    for (int c0 = tid; c0 < VV/4; c0 += 1024*4){ \
      float4 qv[4]; int cb[4]; bool gv[4]; \
      _Pragma("unroll") \
      for (int t=0;t<4;t++){ int cc = c0 + t*1024; gv[t] = (cc < VV/4); cb[t] = cc*4; if (gv[t]) qv[t] = rp[cc]; } \
      _Pragma("unroll") \
      for (int t=0;t<4;t++) if (gv[t]){ \
        float xs[4] = {qv[t].x, qv[t].y, qv[t].z, qv[t].w}; \
        _Pragma("unroll") \
        for (int j=0;j<4;j++){ \
          float x = xs[j]/T; \
          uint32_t u = fkey(x); \
          uint32_t idx = (uint32_t)(cb[t]+j); \
          (void)idx;
#define ROW4_END } } }

__global__ __launch_bounds__(1024) void sampler_kernel(
    const float* __restrict__ logits, const float* __restrict__ temps,
    const int* __restrict__ topks, const float* __restrict__ topps,
    int* __restrict__ out, const uint32_t* __restrict__ ctrs, int mode)
{
  __shared__ __align__(16) uint8_t SM[102400];
  uint32_t* h4    = (uint32_t*)SM;
  ull*      cand  = (ull*)SM;
  uint32_t* h2    = (uint32_t*)(SM + 32*1024);
  ull*      sort2 = (ull*)(SM + 48*1024);
  float*    S     = (float*)SM;
  float*    wf    = (float*)(SM + 16*1024);
  uint32_t* wu    = (uint32_t*)(SM + 64*1024);
  float*    tmpf  = (float*)(SM + 80*1024);
  uint32_t* tmpu  = (uint32_t*)(SM + 84*1024);
  float*    ck    = (float*)(SM + 88*1024);
  ull*      red   = (ull*)(SM + 92*1024);

  __shared__ int s_idx, s_n, s_n2, s_tk, s_ntk, s_tp, s_ntp;
  __shared__ uint32_t s_uk, s_idxk, s_up, s_idxp;
  __shared__ float s_m, s_Zk, s_Ztot;

  const int b   = blockIdx.x;
  const int tid = threadIdx.x;
  const float T = temps[b];
  const int   k = topks[b];
  const float p = topps[b];
  const float* row = logits + (size_t)b * VV;
  const float4* rp = reinterpret_cast<const float4*>(row);
  const bool topk_act = (k > 0) && (k < VV);
  const bool topp_act = (p > 0.0f) && (p < 1.0f);

  const bool ovf = (mode==1) && topk_act && (ctrs[b] > CAPR);
  if (mode==1 && topk_act && !ovf) return;     // handled by fast pipeline

  if (mode==0 && topk_act){
    for (int i=tid;i<4*HN;i+=1024) h4[i]=0u;
    __syncthreads();
    ROW4R_BEGIN
      atomicAdd(&h4[((u>>20)<<2) | (uint32_t)(tid&3)], 1u);
    ROW4R_END
    __syncthreads();
    for (int i=tid;i<HN;i+=1024)
      wu[i] = h4[(i<<2)] + h4[(i<<2)|1] + h4[(i<<2)|2] + h4[(i<<2)|3];
    __syncthreads();
    suffix_scan_u(wu, tmpu, tid);
    if (tid==0) s_idx = 0;
    __syncthreads();
    for (int i=tid;i<HN;i+=1024){
      uint32_t a  = wu[i];
      uint32_t nn = (i+1<HN) ? wu[i+1] : 0u;
      if (a >= (uint32_t)k && nn < (uint32_t)k) s_idx = i;
    }
    __syncthreads();
    const uint32_t beta = (uint32_t)s_idx;
    const int n = (int)wu[beta];
    const uint32_t c_above = (beta+1<HN) ? wu[beta+1] : 0u;
    if (n <= CAP){
      if (tid==0) s_n = 0;
      __syncthreads();
      ROW4R_BEGIN
        if ((u>>20) >= beta){
          int pos = atomicAdd(&s_n, 1);
          cand[pos] = (((ull)(~u))<<32) | idx;
        }
      ROW4R_END
      __syncthreads();
      ull* srt; int m;
      if (n <= 1024){ srt = cand; m = n; }
      else {
        for (int i=tid;i<HN;i+=1024) h2[i]=0u;
        __syncthreads();
        for (int i=tid;i<n;i+=1024){
          uint32_t u2 = ~(uint32_t)(cand[i]>>32);
          if ((u2>>20) == beta) atomicAdd(&h2[(u2>>8)&0xFFFu], 1u);
        }
        __syncthreads();
        suffix_scan_u(h2, tmpu, tid);
        const uint32_t kr = (uint32_t)k - c_above;
        if (tid==0) s_idx = 0;
        __syncthreads();
        for (int i=tid;i<HN;i+=1024){
          uint32_t a  = h2[i];
          uint32_t nn = (i+1<HN) ? h2[i+1] : 0u;
          if (a >= kr && nn < kr) s_idx = i;
        }
        __syncthreads();
        const uint32_t gam = (uint32_t)s_idx;
        const int np = (int)(c_above + h2[gam]);
        if (np <= 1024){
          if (tid==0) s_n2 = 0;
          __syncthreads();
          const uint32_t cut24 = (beta<<12) | gam;
          for (int i=tid;i<n;i+=1024){
            ull e = cand[i];
            uint32_t u2 = ~(uint32_t)(e>>32);
            if ((u2>>8) >= cut24){
              int pos = atomicAdd(&s_n2, 1);
              sort2[pos] = e;
            }
          }
          __syncthreads();
          srt = sort2; m = np;
        } else { srt = cand; m = n; }
      }
      int N = 2; while (N < m) N <<= 1;
      for (int i=tid;i<N;i+=1024) if (i >= m) srt[i] = 0xFFFFFFFFFFFFFFFFull;
      __syncthreads();
      bitonic_sort(srt, N, tid);
      const int kk = k;
      const float xm = keyval(~(uint32_t)(srt[0]>>32)) / T;
      float w = 0.f; uint32_t myidx = 0u;
      if (tid < kk){
        ull e = srt[tid];
        myidx = (uint32_t)e;
        float xv = keyval(~(uint32_t)(e>>32)) / T;
        w = expf(xv - xm);
      }
      ck[tid] = w; __syncthreads();
      for (int d=512; d>0; d>>=1){
        if (tid < d) ck[tid] += ck[tid+d];
        __syncthreads();
      }
      if (tid==0) s_Ztot = ck[0];
      __syncthreads();
      const float Zk = s_Ztot;
      ck[tid] = w / Zk; __syncthreads();
      for (int d=1; d<1024; d<<=1){
        float add = (tid >= d) ? ck[tid-d] : 0.f;
        __syncthreads();
        ck[tid] += add;
        __syncthreads();
      }
      tmpu[tid] = (tid < kk && ck[tid] <= p) ? 1u : 0u;
      __syncthreads();
      for (int d=512; d>0; d>>=1){
        if (tid < d) tmpu[tid] += tmpu[tid+d];
        __syncthreads();
      }
      int L;
      if (!topp_act) L = kk;
      else { int c = (int)tmpu[0]; L = (c >= kk) ? kk : (c + 1); }
      ull best = 0ull;
      if (tid < L){
        float q = w / exp_noise((uint32_t)b * (uint32_t)VV + myidx);
        best = (((ull)__float_as_uint(q)) << 32) | (uint32_t)(~myidx);
      }
      red[tid] = best; __syncthreads();
      for (int d=512; d>0; d>>=1){
        if (tid < d){ ull o = red[tid+d]; if (o > red[tid]) red[tid] = o; }
        __syncthreads();
      }
      if (tid==0) out[b] = (int)(~(uint32_t)(red[0] & 0xFFFFFFFFull));
      return;
    }
    __syncthreads();
  }

  // slow path: k==0, overflow, or mode-0 internal fallthrough
  for (int i=tid;i<HN;i+=1024){ S[i]=0.f; wu[i]=0u; }
  __syncthreads();
  float lmax = -3.4e38f;
  ROW4_BEGIN
    lmax = fmaxf(lmax, x);
    atomicAdd(&wu[u>>20], 1u);
    atomicAdd(&S[u>>20], expf(x));
  ROW4_END
  tmpf[tid] = lmax; __syncthreads();
  for (int d=512; d>0; d>>=1){
    if (tid < d) tmpf[tid] = fmaxf(tmpf[tid], tmpf[tid+d]);
    __syncthreads();
  }
  if (tid==0) s_m = tmpf[0];
  __syncthreads();
  suffix_scan_u(wu, tmpu, tid);
  suffix_scan_f(S,  tmpf, tid);

  uint32_t uk = 0u, idxk = 0xFFFFFFFFu;
  int bk1 = -1;
  if (topk_act){
    if (tid==0) s_idx = 0;
    __syncthreads();
    for (int i=tid;i<HN;i+=1024){
      uint32_t a  = wu[i];
      uint32_t nn = (i+1<HN) ? wu[i+1] : 0u;
      if (a >= (uint32_t)k && nn < (uint32_t)k) s_idx = i;
    }
    __syncthreads();
    bk1 = s_idx;
    const uint32_t c_above1 = (bk1+1<HN) ? wu[bk1+1] : 0u;
    const float    M_above1 = (bk1+1<HN) ? S[bk1+1]  : 0.f;
    __syncthreads();
    for (int i=tid;i<HN;i+=1024){ wu[i]=0u; wf[i]=0.f; }
    __syncthreads();
    ROW4_BEGIN
      if ((int)(u>>20) == bk1){
        atomicAdd(&wu[(u>>8)&0xFFFu], 1u);
        atomicAdd(&wf[(u>>8)&0xFFFu], expf(x));
      }
    ROW4_END
    __syncthreads();
    suffix_scan_u(wu, tmpu, tid);
    suffix_scan_f(wf, tmpf, tid);
    if (tid==0) s_idx = 0;
    __syncthreads();
    for (int i=tid;i<HN;i+=1024){
      uint32_t a  = c_above1 + wu[i];
      uint32_t nn = c_above1 + ((i+1<HN) ? wu[i+1] : 0u);
      if (a >= (uint32_t)k && nn < (uint32_t)k) s_idx = i;
    }
    __syncthreads();
    const int bk2 = s_idx;
    const uint32_t c_above2 = c_above1 + ((bk2+1<HN) ? wu[bk2+1] : 0u);
    const float    M_above2 = M_above1 + ((bk2+1<HN) ? wf[bk2+1] : 0.f);
    __syncthreads();
    if (tid < 256){ wu[tid]=0u; wf[tid]=0.f; }
    __syncthreads();
    const uint32_t top24k = (((uint32_t)bk1)<<12) | (uint32_t)bk2;
    ROW4_BEGIN
      if ((u>>8) == top24k){
        atomicAdd(&wu[u & 0xFFu], 1u);
        atomicAdd(&wf[u & 0xFFu], expf(x));
      }
    ROW4_END
    __syncthreads();
    if (tid==0){
      uint32_t r = 0u; float mr = 0.f; int b3 = 0;
      for (int i=255;i>=0;--i){
        if (c_above2 + r + wu[i] >= (uint32_t)k){ b3 = i; break; }
        r += wu[i]; mr += wf[i];
      }
      const uint32_t cgt = c_above2 + r;
      const float mgt = M_above2 + mr;
      const int nt = (int)wu[b3];
      const int tk = k - (int)cgt;
      s_uk  = (((uint32_t)bk1)<<20) | (((uint32_t)bk2)<<8) | (uint32_t)b3;
      s_tk  = tk; s_ntk = nt;
      s_Zk  = mgt + (float)tk * expf(keyval(s_uk));
      s_n   = 0;
    }
    __syncthreads();
    uk = s_uk;
    if (s_tk < s_ntk){
      ROW4_BEGIN
        if (u == uk){
          int pos = atomicAdd(&s_n, 1);
          if (pos < HN) wu[pos] = idx;
        }
      ROW4_END
      __syncthreads();
      if (tid==0){
        int n2 = min(s_n, HN);
        int t  = min(s_tk, n2);
        s_idxk = select_tth_smallest(wu, n2, t);
      }
      __syncthreads();
      idxk = s_idxk;
    }
  }
  const float Zk = topk_act ? s_Zk : S[0];

  uint32_t up = 0u, idxp = 0xFFFFFFFFu;
  const float tgt = p * Zk;
  const bool pall = (!topp_act) || (tgt >= Zk);
  if (!pall){
    if (tid==0) s_idx = -2;
    __syncthreads();
    for (int i=tid;i<HN;i+=1024){
      if (i > bk1){
        float a  = S[i];
        float nn = (i+1<HN) ? S[i+1] : 0.f;
        if (a > tgt && nn <= tgt) s_idx = i;
      }
    }
    __syncthreads();
    int bp1 = (s_idx >= 0) ? s_idx : bk1;
    if (bp1 < 0) bp1 = 0;
    const float Mab = (bp1+1<HN) ? S[bp1+1] : 0.f;
    __syncthreads();
    for (int i=tid;i<HN;i+=1024) wf[i]=0.f;
    __syncthreads();
    ROW4_BEGIN
      if ((int)(u>>20) == bp1){
        bool kk_ok = (!topk_act) || (u > uk) || (u == uk && idx <= idxk);
        if (kk_ok) atomicAdd(&wf[(u>>8)&0xFFFu], expf(x));
      }
    ROW4_END
    __syncthreads();
    suffix_scan_f(wf, tmpf, tid);
    if (tid==0) s_idx = -2;
    __syncthreads();
    for (int i=tid;i<HN;i+=1024){
      float a  = Mab + wf[i];
      float nn = Mab + ((i+1<HN) ? wf[i+1] : 0.f);
      if (a > tgt && nn <= tgt) s_idx = i;
    }
    __syncthreads();
    int bp2;
    if (s_idx >= 0){ bp2 = s_idx; }
    else {
      if (tid==0) s_idx = HN;
      __syncthreads();
      for (int i=tid;i<HN;i+=1024){
        float a  = wf[i];
        float nn = (i+1<HN) ? wf[i+1] : 0.f;
        if (a > nn) atomicMin(&s_idx, i);
      }
      __syncthreads();
      bp2 = (s_idx < HN) ? s_idx : 0;
    }
    const float Mab2 = Mab + ((bp2+1<HN) ? wf[bp2+1] : 0.f);
    __syncthreads();
    if (tid < 256){ wf[tid]=0.f; wu[tid]=0u; }
    __syncthreads();
    const uint32_t top24p = (((uint32_t)bp1)<<12) | (uint32_t)bp2;
    ROW4_BEGIN
      if ((u>>8) == top24p){
        bool kk_ok = (!topk_act) || (u > uk) || (u == uk && idx <= idxk);
        if (kk_ok){
          atomicAdd(&wf[u & 0xFFu], expf(x));
          atomicAdd(&wu[u & 0xFFu], 1u);
        }
      }
    ROW4_END
    __syncthreads();
    if (tid==0){
      float run = 0.f; int b3 = -1; float mgt = 0.f;
      for (int i=255;i>=0;--i){
        float sufn = run; run += wf[i];
        if (Mab2 + run > tgt && Mab2 + sufn <= tgt){ b3 = i; mgt = Mab2 + sufn; break; }
      }
      if (b3 < 0){
        float run2 = 0.f;
        for (int i=255;i>=0;--i){
          if (wu[i] > 0u){ b3 = i; mgt = Mab2 + run2; }
          run2 += wf[i];
        }
        if (b3 < 0){ b3 = 0; mgt = Mab2; }
      }
      const uint32_t upv = (((uint32_t)bp1)<<20) | (((uint32_t)bp2)<<8) | (uint32_t)b3;
      const int ntp = (int)wu[b3];
      const float ev = expf(keyval(upv));
      int t = 0;
      for (int j=1;j<=ntp;j++){
        float before = mgt + (float)(j-1) * ev;
        if (before / Zk <= p) t++; else break;
      }
      if (t < 1) t = 1;
      s_up = upv; s_tp = t; s_ntp = ntp; s_n = 0;
    }
    __syncthreads();
    up = s_up;
    if (s_tp < s_ntp){
      ROW4_BEGIN
        if (u == up){
          bool kk_ok = (!topk_act) || (u > uk) || (u == uk && idx <= idxk);
          if (kk_ok){
            int pos = atomicAdd(&s_n, 1);
            if (pos < HN) wu[pos] = idx;
          }
        }
      ROW4_END
      __syncthreads();
      if (tid==0){
        int n2 = min(s_n, HN);
        int t  = min(s_tp, n2);
        s_idxp = select_tth_smallest(wu, n2, t);
      }
      __syncthreads();
      idxp = s_idxp;
    }
  }

  const float m  = s_m;
  const float Zs = Zk * expf(-m);
  ull best = 0ull;
  ROW4_BEGIN
    bool kk_ok = (!topk_act) || (u > uk) || (u == uk && idx <= idxk);
    bool kp_ok = pall || (u > up) || (u == up && idx <= idxp);
    if (kk_ok && kp_ok){
      float q = (expf(x - m) / Zs) / exp_noise((uint32_t)b * (uint32_t)VV + idx);
      ull pk = (((ull)__float_as_uint(q)) << 32) | (uint32_t)(~idx);
      best = (pk > best) ? pk : best;
    }
  ROW4_END
  red[tid] = best; __syncthreads();
  for (int d=512; d>0; d>>=1){
    if (tid < d){ ull o = red[tid+d]; if (o > red[tid]) red[tid] = o; }
    __syncthreads();
  }
  if (tid==0) out[b] = (int)(~(uint32_t)(red[0] & 0xFFFFFFFFull));
}

extern "C" void kernel_launch(void* const* d_in, const int* in_sizes, int n_in,
                              void* d_out, int out_size, void* d_ws, size_t ws_size,
                              hipStream_t stream) {
  (void)in_sizes; (void)n_in; (void)out_size;
  const float* logits = (const float*)d_in[0];
  const float* temps  = (const float*)d_in[1];
  const int*   ks     = (const int*)d_in[2];
  const float* ps     = (const float*)d_in[3];
  int* out = (int*)d_out;

  const size_t HIST_BYTES = (size_t)256*HN*4;        // 4,194,304
  const size_t CTR_BYTES  = 1024;
  const size_t CAND_BYTES = (size_t)256*CAPR*8;      // 16,777,216
  const size_t NEED = HIST_BYTES + CTR_BYTES + CAND_BYTES;

  if (ws_size >= NEED && d_ws != nullptr){
    uint8_t* ws = (uint8_t*)d_ws;
    uint32_t* hists = (uint32_t*)ws;
    uint32_t* ctrs  = (uint32_t*)(ws + HIST_BYTES);
    ull*      cands = (ull*)(ws + HIST_BYTES + CTR_BYTES);
    hipMemsetAsync(ws, 0, HIST_BYTES + CTR_BYTES, stream);
    hist_kernel  <<<2048, 256, 0, stream>>>(logits, hists);
    gather_kernel<<<2048, 256, 0, stream>>>(logits, ks, hists, ctrs, cands);
    select_kernel<<<256, 1024, 0, stream>>>(temps, ks, ps, ctrs, cands, out);
    sampler_kernel<<<256, 1024, 0, stream>>>(logits, temps, ks, ps, out, ctrs, 1);
  } else {
    sampler_kernel<<<256, 1024, 0, stream>>>(logits, temps, ks, ps, out, nullptr, 0);
  }
}